// Round 2
// baseline (1952.214 us; speedup 1.0000x reference)
//
#include <hip/hip_runtime.h>

#define DD 512
#define NBLK 24

typedef short s16x8 __attribute__((ext_vector_type(8)));
typedef float f32x4 __attribute__((ext_vector_type(4)));

union FragU { s16x8 s; __bf16 h[8]; };

__device__ __forceinline__ f32x4 mfma16(s16x8 a, s16x8 b, f32x4 c) {
  return __builtin_amdgcn_mfma_f32_16x16x32_bf16(a, b, c, 0, 0, 0);
}

// split-bf16: v = hi + lo, |v - hi - lo| <= 2^-16 |v|
__device__ __forceinline__ void bsplit(float v, __bf16& hi, __bf16& lo) {
  hi = (__bf16)v;
  lo = (__bf16)(v - (float)hi);
}

// ---------------------------------------------------------------------------
// LDS-free 64xN GEMM (f32-accurate via 3-term split-bf16 MFMA):
// out[m][n] = epilogue( sum_k A[m][k]*W[k][n] + bias[n] )
// M=64 (4 waves x 16 rows), wg covers cols [n0, n0+64).
// Arow = Abase + (row>>rshift)*sOuter + (row & mask)*512 (f32).
// AMODE: 0 raw, 1 relu(A), 2 layernorm(A)
// ---------------------------------------------------------------------------
template<int AMODE, bool RESID>
__device__ __forceinline__ void gemm64_core(
    const float* __restrict__ Abase, int rshift, long sOuter,
    const float* __restrict__ Wf,
    const float* __restrict__ bias,
    const float* __restrict__ lng, const float* __restrict__ lnb,
    const float* __restrict__ resid,
    float* __restrict__ outF,
    int n0)
{
  const int tid  = threadIdx.x;
  const int wave = tid >> 6;
  const int lane = tid & 63;
  const int l15  = lane & 15;
  const int lq   = lane >> 4;            // 0..3

  const int rowA = wave * 16 + l15;
  const float* Arow = Abase + (long)(rowA >> rshift) * sOuter
                            + (long)(rowA & ((1 << rshift) - 1)) * DD;

  float mu = 0.f, rstd = 0.f;
  if constexpr (AMODE == 2) {
    float s = 0.f, ss = 0.f;
    const float* p = Arow + lq * 128;
    #pragma unroll
    for (int k = 0; k < 128; k += 4) {
      float4 v = *reinterpret_cast<const float4*>(p + k);
      s  += v.x + v.y + v.z + v.w;
      ss += v.x * v.x + v.y * v.y + v.z * v.z + v.w * v.w;
    }
    s += __shfl_xor(s, 16); ss += __shfl_xor(ss, 16);
    s += __shfl_xor(s, 32); ss += __shfl_xor(ss, 32);
    mu = s * (1.f / 512.f);
    float var = ss * (1.f / 512.f) - mu * mu;
    rstd = rsqrtf(var + 1e-5f);
  }

  f32x4 acc[4] = {};

  for (int ks = 0; ks < 16; ++ks) {
    const int k0 = ks * 32 + lq * 8;
    FragU ahi, alo;
    {
      float4 v0 = *reinterpret_cast<const float4*>(Arow + k0);
      float4 v1 = *reinterpret_cast<const float4*>(Arow + k0 + 4);
      float t0[8] = {v0.x, v0.y, v0.z, v0.w, v1.x, v1.y, v1.z, v1.w};
      if constexpr (AMODE == 2) {
        float4 g0 = *reinterpret_cast<const float4*>(lng + k0);
        float4 g1 = *reinterpret_cast<const float4*>(lng + k0 + 4);
        float4 c0 = *reinterpret_cast<const float4*>(lnb + k0);
        float4 c1 = *reinterpret_cast<const float4*>(lnb + k0 + 4);
        float gg[8] = {g0.x, g0.y, g0.z, g0.w, g1.x, g1.y, g1.z, g1.w};
        float cc[8] = {c0.x, c0.y, c0.z, c0.w, c1.x, c1.y, c1.z, c1.w};
        #pragma unroll
        for (int e = 0; e < 8; ++e) {
          float v = (t0[e] - mu) * rstd * gg[e] + cc[e];
          bsplit(v, ahi.h[e], alo.h[e]);
        }
      } else {
        #pragma unroll
        for (int e = 0; e < 8; ++e) {
          float v = t0[e];
          if constexpr (AMODE == 1) v = fmaxf(v, 0.f);
          bsplit(v, ahi.h[e], alo.h[e]);
        }
      }
    }
    const float* wp = Wf + (long)k0 * DD + n0 + l15;
    #pragma unroll
    for (int j = 0; j < 4; ++j) {
      FragU bhi, blo;
      #pragma unroll
      for (int e = 0; e < 8; ++e) {
        float w = wp[(long)e * DD + j * 16];
        bsplit(w, bhi.h[e], blo.h[e]);
      }
      acc[j] = mfma16(ahi.s, bhi.s, acc[j]);
      acc[j] = mfma16(ahi.s, blo.s, acc[j]);
      acc[j] = mfma16(alo.s, bhi.s, acc[j]);
    }
  }

  const int mbase = wave * 16 + lq * 4;  // D rows: (lane>>4)*4 + reg
  #pragma unroll
  for (int j = 0; j < 4; ++j) {
    const int n = n0 + j * 16 + l15;
    const float bv = bias[n];
    #pragma unroll
    for (int r = 0; r < 4; ++r) {
      const int m = mbase + r;
      float v = acc[j][r] + bv;
      if constexpr (RESID) v += fmaxf(resid[(long)m * DD + n], 0.f);
      outF[(long)m * DD + n] = v;
    }
  }
}

// ---------------------------------------------------------------------------
// Phase-1: kt/vt for all blocks. One wg = 64x64 tile for all 4 outputs
// o = arm*2+kv (shared A tile), split-bf16 hi/lo LDS planes, f32 output.
// ---------------------------------------------------------------------------
#define LDSW 40   // padded bf16 row stride

__global__ __launch_bounds__(256) void k_p1t(
    const float* __restrict__ ahs,
    const float* __restrict__ WL, const float* __restrict__ WR,
    const float* __restrict__ bL, const float* __restrict__ bR,
    float* __restrict__ kvt)
{
  __shared__ __align__(16) unsigned short Ab[2][64 * LDSW];
  __shared__ __align__(16) unsigned short Wb[4][2][64 * LDSW];

  const int bx = blockIdx.x;
  const int ntile = bx & 7, mtile = (bx >> 3) & 7, nb = bx >> 6;
  const int n0 = ntile * 64;

  const float* Abase = ahs + (long)(mtile * 25 + nb + 1) * 80 * DD; // t=0..63
  const float* Wp[4];
  const float* bp[4];
  #pragma unroll
  for (int o = 0; o < 4; ++o) {
    const int arm = o >> 1, kv = o & 1;
    Wp[o] = (arm ? WR : WL) + (long)(nb * 11 + 3 + kv) * DD * DD;
    bp[o] = (arm ? bR : bL) + (long)(nb * 11 + 3 + kv) * DD;
  }

  const int tid  = threadIdx.x;
  const int srow = tid >> 2;         // A row / W col within tile (0..63)
  const int skq  = (tid & 3) * 8;    // k offset within 32-wide step
  const int wave = tid >> 6, lane = tid & 63, l15 = lane & 15, lq = lane >> 4;

  f32x4 acc[4][4] = {};
  float aR[8];
  float wRg[4][8];

  auto loadStage = [&](int kbase) {
    const float* ap = Abase + (long)srow * DD + kbase + skq;
    float4 v0 = *reinterpret_cast<const float4*>(ap);
    float4 v1 = *reinterpret_cast<const float4*>(ap + 4);
    aR[0] = v0.x; aR[1] = v0.y; aR[2] = v0.z; aR[3] = v0.w;
    aR[4] = v1.x; aR[5] = v1.y; aR[6] = v1.z; aR[7] = v1.w;
    #pragma unroll
    for (int o = 0; o < 4; ++o) {
      #pragma unroll
      for (int e = 0; e < 8; ++e)
        wRg[o][e] = Wp[o][(long)(kbase + skq + e) * DD + n0 + srow];
    }
  };

  loadStage(0);
  for (int s = 0; s < 16; ++s) {
    __syncthreads();
    {
      FragU uh, ul;
      #pragma unroll
      for (int e = 0; e < 8; ++e) bsplit(aR[e], uh.h[e], ul.h[e]);
      *reinterpret_cast<s16x8*>(&Ab[0][srow * LDSW + skq]) = uh.s;
      *reinterpret_cast<s16x8*>(&Ab[1][srow * LDSW + skq]) = ul.s;
      #pragma unroll
      for (int o = 0; o < 4; ++o) {
        FragU wh, wl;
        #pragma unroll
        for (int e = 0; e < 8; ++e) bsplit(wRg[o][e], wh.h[e], wl.h[e]);
        *reinterpret_cast<s16x8*>(&Wb[o][0][srow * LDSW + skq]) = wh.s;
        *reinterpret_cast<s16x8*>(&Wb[o][1][srow * LDSW + skq]) = wl.s;
      }
    }
    __syncthreads();
    if (s < 15) loadStage((s + 1) * 32);   // overlaps with MFMA below
    s16x8 ahi = *reinterpret_cast<const s16x8*>(&Ab[0][(wave * 16 + l15) * LDSW + lq * 8]);
    s16x8 alo = *reinterpret_cast<const s16x8*>(&Ab[1][(wave * 16 + l15) * LDSW + lq * 8]);
    #pragma unroll
    for (int o = 0; o < 4; ++o) {
      #pragma unroll
      for (int j = 0; j < 4; ++j) {
        s16x8 bhi = *reinterpret_cast<const s16x8*>(&Wb[o][0][(j * 16 + l15) * LDSW + lq * 8]);
        s16x8 blo = *reinterpret_cast<const s16x8*>(&Wb[o][1][(j * 16 + l15) * LDSW + lq * 8]);
        acc[o][j] = mfma16(ahi, bhi, acc[o][j]);
        acc[o][j] = mfma16(ahi, blo, acc[o][j]);
        acc[o][j] = mfma16(alo, bhi, acc[o][j]);
      }
    }
  }

  const int mbase = mtile * 64 + wave * 16 + lq * 4;
  #pragma unroll
  for (int o = 0; o < 4; ++o) {
    float* outb = kvt + (long)(nb * 4 + o) * 512 * DD;
    #pragma unroll
    for (int j = 0; j < 4; ++j) {
      const int n = n0 + j * 16 + l15;
      const float bv = bp[o][n];
      #pragma unroll
      for (int r = 0; r < 4; ++r)
        outb[(long)(mbase + r) * DD + n] = acc[o][j][r] + bv;
    }
  }
}

// Phase-1: ka/va (M=64, h_a rows: b = row>>3, t = 64+arm*8+(row&7))
__global__ __launch_bounds__(256) void k_p1a(
    const float* __restrict__ ahs,
    const float* __restrict__ WL, const float* __restrict__ WR,
    const float* __restrict__ bL, const float* __restrict__ bR,
    float* __restrict__ kva)
{
  const int bx = blockIdx.x;
  const int ntile = bx & 7, kv = (bx >> 3) & 1, arm = (bx >> 4) & 1, nb = bx >> 5;
  const float* Abase = ahs + ((long)(nb + 1) * 80 + 64 + arm * 8) * DD;
  const float* W    = (arm ? WR : WL) + (long)(nb * 11 + 5 + kv) * DD * DD;
  const float* bias = (arm ? bR : bL) + (long)(nb * 11 + 5 + kv) * DD;
  float* out = kva + (long)(nb * 4 + arm * 2 + kv) * 64 * DD;
  gemm64_core<0, false>(Abase, 3, (long)25 * 80 * DD, W, bias,
                        nullptr, nullptr, nullptr, out, ntile * 64);
}

// Sequential: q,ks,vs from relu(x_self); ki,vi from relu(x_other)
__global__ __launch_bounds__(256) void k_qkv(
    const float* __restrict__ x,
    const float* __restrict__ WL, const float* __restrict__ WR,
    const float* __restrict__ bL, const float* __restrict__ bR,
    float* __restrict__ qkv, int nb)
{
  const int bx = blockIdx.x;
  const int arm = bx / 40;
  const int rem = bx - arm * 40;
  const int wi = rem >> 3, ntile = rem & 7;
  const int w = (wi < 3) ? wi : wi + 4;                 // {0,1,2,7,8}
  const float* A    = x + (long)((wi < 3) ? arm : (1 - arm)) * 64 * DD;
  const float* W    = (arm ? WR : WL) + (long)(nb * 11 + w) * DD * DD;
  const float* bias = (arm ? bR : bL) + (long)(nb * 11 + w) * DD;
  float* out = qkv + (long)(arm * 5 + wi) * 64 * DD;
  gemm64_core<1, false>(A, 6, 0, W, bias, nullptr, nullptr, nullptr,
                        out, ntile * 64);
}

// Sequential: attention per (arm, b, h). Keys: [ks(rope), ka, g*kt, ki(rope)]
__global__ __launch_bounds__(512) void k_attn(
    const float* __restrict__ qkv, const float* __restrict__ kvt,
    const float* __restrict__ kva, const float* __restrict__ gating,
    const float* __restrict__ ropeC, const float* __restrict__ ropeS,
    float* __restrict__ attnout, int nb)
{
  __shared__ float kb[88 * 65];
  __shared__ float vb[88 * 65];
  __shared__ float qb[8 * 65];
  __shared__ float pb[8 * 89];

  const int bx = blockIdx.x;
  const int h = bx & 7, b = (bx >> 3) & 7, arm = bx >> 6;
  const int tid = threadIdx.x;
  const float g = tanhf(gating[nb]);

  {
    const int p = tid >> 6, d = tid & 63;
    const float* qrow = qkv + ((long)(arm * 5 + 0) * 64 + b * 8 + p) * DD + h * 64;
    float v = qrow[d], vp = qrow[d ^ 1];
    float c = ropeC[p * 64 + d], s = ropeS[p * 64 + d];
    qb[p * 65 + d] = v * c + ((d & 1) ? vp : -vp) * s;
  }
  for (int idx = tid; idx < 88 * 64; idx += 512) {
    const int j = idx >> 6, d = idx & 63;
    float kvval, vvval;
    if (j < 8) {                                   // ks (rope pos j), vs
      const float* krow = qkv + ((long)(arm * 5 + 1) * 64 + b * 8 + j) * DD + h * 64;
      float v = krow[d], vp = krow[d ^ 1];
      float c = ropeC[j * 64 + d], s = ropeS[j * 64 + d];
      kvval = v * c + ((d & 1) ? vp : -vp) * s;
      vvval = qkv[((long)(arm * 5 + 2) * 64 + b * 8 + j) * DD + h * 64 + d];
    } else if (j < 16) {                           // ka, va
      const int t = j - 8;
      kvval = kva[((long)(nb * 4 + arm * 2 + 0) * 64 + b * 8 + t) * DD + h * 64 + d];
      vvval = kva[((long)(nb * 4 + arm * 2 + 1) * 64 + b * 8 + t) * DD + h * 64 + d];
    } else if (j < 80) {                           // g*kt, vt
      const int t = j - 16;
      kvval = g * kvt[((long)(nb * 4 + arm * 2 + 0) * 512 + b * 64 + t) * DD + h * 64 + d];
      vvval = kvt[((long)(nb * 4 + arm * 2 + 1) * 512 + b * 64 + t) * DD + h * 64 + d];
    } else {                                       // ki (rope pos t), vi
      const int t = j - 80;
      const float* krow = qkv + ((long)(arm * 5 + 3) * 64 + b * 8 + t) * DD + h * 64;
      float v = krow[d], vp = krow[d ^ 1];
      float c = ropeC[t * 64 + d], s = ropeS[t * 64 + d];
      kvval = v * c + ((d & 1) ? vp : -vp) * s;
      vvval = qkv[((long)(arm * 5 + 4) * 64 + b * 8 + t) * DD + h * 64 + d];
    }
    kb[j * 65 + d] = kvval;
    vb[j * 65 + d] = vvval;
  }
  __syncthreads();

  const int p = tid >> 6, lane = tid & 63;
  float s0 = 0.f, s1 = 0.f;
  const int j2 = 64 + ((lane < 24) ? lane : 0);
  #pragma unroll 8
  for (int d = 0; d < 64; ++d) {
    const float q = qb[p * 65 + d];
    s0 += q * kb[lane * 65 + d];
    s1 += q * kb[j2 * 65 + d];
  }
  s0 *= 0.125f; s1 *= 0.125f;
  float m = (lane < 24) ? fmaxf(s0, s1) : s0;
  #pragma unroll
  for (int off = 1; off < 64; off <<= 1) m = fmaxf(m, __shfl_xor(m, off));
  const float e0 = __expf(s0 - m);
  const float e1 = (lane < 24) ? __expf(s1 - m) : 0.f;
  float sum = e0 + e1;
  #pragma unroll
  for (int off = 1; off < 64; off <<= 1) sum += __shfl_xor(sum, off);
  const float inv = 1.f / sum;
  pb[p * 89 + lane] = e0 * inv;
  if (lane < 24) pb[p * 89 + 64 + lane] = e1 * inv;
  __syncthreads();

  float acc = 0.f;
  #pragma unroll 8
  for (int j = 0; j < 88; ++j) acc += pb[p * 89 + j] * vb[j * 65 + lane];
  attnout[((long)arm * 64 + b * 8 + p) * DD + h * 64 + lane] = acc;
}

// Sequential: y = attnout @ W9 + b9 + relu(x)
__global__ __launch_bounds__(256) void k_proj(
    const float* __restrict__ attnout,
    const float* __restrict__ WL, const float* __restrict__ WR,
    const float* __restrict__ bL, const float* __restrict__ bR,
    const float* __restrict__ x, float* __restrict__ y, int nb)
{
  const int bx = blockIdx.x;
  const int arm = bx >> 3, ntile = bx & 7;
  const float* A    = attnout + (long)arm * 64 * DD;
  const float* W    = (arm ? WR : WL) + (long)(nb * 11 + 9) * DD * DD;
  const float* bias = (arm ? bR : bL) + (long)(nb * 11 + 9) * DD;
  gemm64_core<0, true>(A, 6, 0, W, bias, nullptr, nullptr,
                       x + (long)arm * 64 * DD,
                       y + (long)arm * 64 * DD, ntile * 64);
}

// Sequential: x_next(pre-relu) = LN(y; lng,lnb) @ W10 + b10
__global__ __launch_bounds__(256) void k_ffn(
    const float* __restrict__ y,
    const float* __restrict__ WL, const float* __restrict__ WR,
    const float* __restrict__ bL, const float* __restrict__ bR,
    const float* __restrict__ lngL, const float* __restrict__ lnbL,
    const float* __restrict__ lngR, const float* __restrict__ lnbR,
    float* __restrict__ x, int nb)
{
  const int bx = blockIdx.x;
  const int arm = bx >> 3, ntile = bx & 7;
  const float* A    = y + (long)arm * 64 * DD;
  const float* W    = (arm ? WR : WL) + (long)(nb * 11 + 10) * DD * DD;
  const float* bias = (arm ? bR : bL) + (long)(nb * 11 + 10) * DD;
  const float* g    = (arm ? lngR : lngL) + (long)nb * DD;
  const float* bb   = (arm ? lnbR : lnbL) + (long)nb * DD;
  gemm64_core<2, false>(A, 6, 0, W, bias, g, bb, nullptr,
                        x + (long)arm * 64 * DD, ntile * 64);
}

// Final: out[b,p, arm*7+j] = LN(relu(x)) @ fcW + fcb
__global__ __launch_bounds__(64) void k_final(
    const float* __restrict__ x,
    const float* __restrict__ fgL, const float* __restrict__ fbL,
    const float* __restrict__ fgR, const float* __restrict__ fbR,
    const float* __restrict__ fwL, const float* __restrict__ fcbL,
    const float* __restrict__ fwR, const float* __restrict__ fcbR,
    float* __restrict__ out)
{
  const int bx = blockIdx.x;
  const int b = bx & 7, arm = bx >> 3;
  const int tid = threadIdx.x;
  const int p = tid >> 3, k8 = tid & 7;
  const float* xr = x + ((long)arm * 64 + b * 8 + p) * DD;

  float s = 0.f, ss = 0.f;
  for (int k = k8 * 64; k < k8 * 64 + 64; k += 4) {
    float4 v = *reinterpret_cast<const float4*>(xr + k);
    float a0 = fmaxf(v.x, 0.f), a1 = fmaxf(v.y, 0.f);
    float a2 = fmaxf(v.z, 0.f), a3 = fmaxf(v.w, 0.f);
    s  += a0 + a1 + a2 + a3;
    ss += a0 * a0 + a1 * a1 + a2 * a2 + a3 * a3;
  }
  s += __shfl_xor(s, 1); ss += __shfl_xor(ss, 1);
  s += __shfl_xor(s, 2); ss += __shfl_xor(ss, 2);
  s += __shfl_xor(s, 4); ss += __shfl_xor(ss, 4);
  const float mu = s * (1.f / 512.f);
  const float var = ss * (1.f / 512.f) - mu * mu;
  const float rstd = rsqrtf(var + 1e-5f);

  const float* g   = arm ? fgR : fgL;
  const float* bb  = arm ? fbR : fbL;
  const float* fw  = arm ? fwR : fwL;
  const float* fcb = arm ? fcbR : fcbL;
  const int j = k8;
  if (j < 7) {
    float acc = 0.f;
    for (int k = 0; k < 512; ++k) {
      const float xn = (fmaxf(xr[k], 0.f) - mu) * rstd * g[k] + bb[k];
      acc += xn * fw[k * 7 + j];
    }
    out[((long)(b * 8) + p) * 14 + arm * 7 + j] = acc + fcb[j];
  }
}

// Init: x = 0 (scan carry) + RoPE tables (8 pos x 64 dims)
__global__ void k_init(float* __restrict__ x, float* __restrict__ ropeC,
                       float* __restrict__ ropeS)
{
  const int t = blockIdx.x * 256 + threadIdx.x;
  if (t < 2 * 64 * DD) x[t] = 0.f;
  if (t < 512) {
    const int p = t >> 6, d = t & 63;
    const float inv = expf(-(float)(d & 31) * (9.210340371976184f / 32.f)); // 10000^(-(d&31)/32)
    const float ang = (float)p * inv;
    ropeC[t] = cosf(ang);
    ropeS[t] = sinf(ang);
  }
}

extern "C" void kernel_launch(void* const* d_in, const int* in_sizes, int n_in,
                              void* d_out, int out_size, void* d_ws, size_t ws_size,
                              hipStream_t stream)
{
  (void)in_sizes; (void)n_in; (void)out_size; (void)ws_size;

  const float* ahs  = (const float*)d_in[0];
  const float* WL   = (const float*)d_in[1];
  const float* bL   = (const float*)d_in[2];
  const float* lngL = (const float*)d_in[3];
  const float* lnbL = (const float*)d_in[4];
  const float* WR   = (const float*)d_in[5];
  const float* bR   = (const float*)d_in[6];
  const float* lngR = (const float*)d_in[7];
  const float* lnbR = (const float*)d_in[8];
  const float* gating = (const float*)d_in[9];
  const float* fgL  = (const float*)d_in[10];
  const float* fbL  = (const float*)d_in[11];
  const float* fgR  = (const float*)d_in[12];
  const float* fbR  = (const float*)d_in[13];
  const float* fwL  = (const float*)d_in[14];
  const float* fcbL = (const float*)d_in[15];
  const float* fwR  = (const float*)d_in[16];
  const float* fcbR = (const float*)d_in[17];
  float* out = (float*)d_out;

  char* ws = (char*)d_ws;
  size_t off = 0;
  float* ropeC = (float*)(ws + off); off += 512 * 4;
  float* ropeS = (float*)(ws + off); off += 512 * 4;
  float* x     = (float*)(ws + off); off += (size_t)2 * 64 * DD * 4;
  float* qkv   = (float*)(ws + off); off += (size_t)2 * 5 * 64 * DD * 4;
  float* attno = (float*)(ws + off); off += (size_t)2 * 64 * DD * 4;
  float* y     = (float*)(ws + off); off += (size_t)2 * 64 * DD * 4;
  float* kvt   = (float*)(ws + off); off += (size_t)NBLK * 4 * 512 * DD * 4;
  float* kva   = (float*)(ws + off); off += (size_t)NBLK * 4 * 64 * DD * 4;

  k_init<<<dim3(256), dim3(256), 0, stream>>>(x, ropeC, ropeS);
  k_p1t <<<dim3(1536), dim3(256), 0, stream>>>(ahs, WL, WR, bL, bR, kvt);
  k_p1a <<<dim3(768),  dim3(256), 0, stream>>>(ahs, WL, WR, bL, bR, kva);

  for (int nb = 0; nb < NBLK; ++nb) {
    k_qkv <<<dim3(80),  dim3(256), 0, stream>>>(x, WL, WR, bL, bR, qkv, nb);
    k_attn<<<dim3(128), dim3(512), 0, stream>>>(qkv, kvt, kva, gating, ropeC, ropeS, attno, nb);
    k_proj<<<dim3(16),  dim3(256), 0, stream>>>(attno, WL, WR, bL, bR, x, y, nb);
    k_ffn <<<dim3(16),  dim3(256), 0, stream>>>(y, WL, WR, bL, bR, lngL, lnbL, lngR, lnbR, x, nb);
  }
  k_final<<<dim3(16), dim3(64), 0, stream>>>(x, fgL, fbL, fgR, fbR, fwL, fcbL, fwR, fcbR, out);
}

// Round 3
// 1858.288 us; speedup vs baseline: 1.0505x; 1.0505x over previous
//
#include <hip/hip_runtime.h>

#define DD 512
#define NBLK 24
#define BLK (64 * DD)            // one 64-row arm block (floats)
#define WT_SLOT 524288           // shorts per transposed matrix (512*512*2)

typedef short s16x8 __attribute__((ext_vector_type(8)));
typedef float f32x4 __attribute__((ext_vector_type(4)));

union FragU { s16x8 s; __bf16 h[8]; };

__device__ __forceinline__ f32x4 mfma16(s16x8 a, s16x8 b, f32x4 c) {
  return __builtin_amdgcn_mfma_f32_16x16x32_bf16(a, b, c, 0, 0, 0);
}

__device__ __forceinline__ void bsplit(float v, __bf16& hi, __bf16& lo) {
  hi = (__bf16)v;
  lo = (__bf16)(v - (float)hi);
}
__device__ __forceinline__ unsigned short f2hi(float v) {
  union { __bf16 h; unsigned short u; } cv; cv.h = (__bf16)v; return cv.u;
}

// ---------------------------------------------------------------------------
// OLD gather core (kept for k_p1a and the ws-too-small fallback path)
// ---------------------------------------------------------------------------
template<int AMODE, bool RESID>
__device__ __forceinline__ void gemm64_core(
    const float* __restrict__ Abase, int rshift, long sOuter,
    const float* __restrict__ Wf,
    const float* __restrict__ bias,
    const float* __restrict__ lng, const float* __restrict__ lnb,
    const float* __restrict__ resid,
    float* __restrict__ outF,
    int n0)
{
  const int tid  = threadIdx.x;
  const int wave = tid >> 6;
  const int lane = tid & 63;
  const int l15  = lane & 15;
  const int lq   = lane >> 4;

  const int rowA = wave * 16 + l15;
  const float* Arow = Abase + (long)(rowA >> rshift) * sOuter
                            + (long)(rowA & ((1 << rshift) - 1)) * DD;

  float mu = 0.f, rstd = 0.f;
  if constexpr (AMODE == 2) {
    float s = 0.f, ss = 0.f;
    const float* p = Arow + lq * 128;
    #pragma unroll
    for (int k = 0; k < 128; k += 4) {
      float4 v = *reinterpret_cast<const float4*>(p + k);
      s  += v.x + v.y + v.z + v.w;
      ss += v.x * v.x + v.y * v.y + v.z * v.z + v.w * v.w;
    }
    s += __shfl_xor(s, 16); ss += __shfl_xor(ss, 16);
    s += __shfl_xor(s, 32); ss += __shfl_xor(ss, 32);
    mu = s * (1.f / 512.f);
    float var = ss * (1.f / 512.f) - mu * mu;
    rstd = rsqrtf(var + 1e-5f);
  }

  f32x4 acc[4] = {};

  for (int ks = 0; ks < 16; ++ks) {
    const int k0 = ks * 32 + lq * 8;
    FragU ahi, alo;
    {
      float4 v0 = *reinterpret_cast<const float4*>(Arow + k0);
      float4 v1 = *reinterpret_cast<const float4*>(Arow + k0 + 4);
      float t0[8] = {v0.x, v0.y, v0.z, v0.w, v1.x, v1.y, v1.z, v1.w};
      if constexpr (AMODE == 2) {
        float4 g0 = *reinterpret_cast<const float4*>(lng + k0);
        float4 g1 = *reinterpret_cast<const float4*>(lng + k0 + 4);
        float4 c0 = *reinterpret_cast<const float4*>(lnb + k0);
        float4 c1 = *reinterpret_cast<const float4*>(lnb + k0 + 4);
        float gg[8] = {g0.x, g0.y, g0.z, g0.w, g1.x, g1.y, g1.z, g1.w};
        float cc[8] = {c0.x, c0.y, c0.z, c0.w, c1.x, c1.y, c1.z, c1.w};
        #pragma unroll
        for (int e = 0; e < 8; ++e) {
          float v = (t0[e] - mu) * rstd * gg[e] + cc[e];
          bsplit(v, ahi.h[e], alo.h[e]);
        }
      } else {
        #pragma unroll
        for (int e = 0; e < 8; ++e) {
          float v = t0[e];
          if constexpr (AMODE == 1) v = fmaxf(v, 0.f);
          bsplit(v, ahi.h[e], alo.h[e]);
        }
      }
    }
    const float* wp = Wf + (long)k0 * DD + n0 + l15;
    #pragma unroll
    for (int j = 0; j < 4; ++j) {
      FragU bhi, blo;
      #pragma unroll
      for (int e = 0; e < 8; ++e) {
        float w = wp[(long)e * DD + j * 16];
        bsplit(w, bhi.h[e], blo.h[e]);
      }
      acc[j] = mfma16(ahi.s, bhi.s, acc[j]);
      acc[j] = mfma16(ahi.s, blo.s, acc[j]);
      acc[j] = mfma16(alo.s, bhi.s, acc[j]);
    }
  }

  const int mbase = wave * 16 + lq * 4;
  #pragma unroll
  for (int j = 0; j < 4; ++j) {
    const int n = n0 + j * 16 + l15;
    const float bv = bias[n];
    #pragma unroll
    for (int r = 0; r < 4; ++r) {
      const int m = mbase + r;
      float v = acc[j][r] + bv;
      if constexpr (RESID) v += fmaxf(resid[(long)m * DD + n], 0.f);
      outF[(long)m * DD + n] = v;
    }
  }
}

// ---------------------------------------------------------------------------
// NEW: fragment-native transposed-weight core.
// Wt slot layout: [ng(32)][k8(64)][l(16)][hi e0..7 | lo e0..7]  (shorts)
//   element (k = k8*8+e, n = ng*16+l).
// Tile: 16 cols (n0..n0+15), 64 rows (wave = m/16). K-range [ks0,ks1).
// AMODE: 0 raw, 1 relu, 2 layernorm.  A = A1 (+A2 if A2P).
// resid (r1[,r2]) applied as += relu(r1+r2) when r1 != nullptr.
// ---------------------------------------------------------------------------
template<int AMODE, bool A2P>
__device__ __forceinline__ void gemm16t(
    const float* __restrict__ A1, const float* __restrict__ A2,
    const unsigned short* __restrict__ Wt,   // slot base
    const float* __restrict__ bias, int addBias,
    const float* __restrict__ lng, const float* __restrict__ lnb,
    const float* __restrict__ r1, const float* __restrict__ r2,
    float* __restrict__ outF, int n0, int ks0, int ks1)
{
  const int tid  = threadIdx.x;
  const int wave = tid >> 6;
  const int lane = tid & 63;
  const int l15  = lane & 15;
  const int lq   = lane >> 4;

  const int rowA = wave * 16 + l15;
  const float* A1row = A1 + (long)rowA * DD;
  const float* A2row = A2P ? (A2 + (long)rowA * DD) : nullptr;

  float mu = 0.f, rstd = 0.f;
  if constexpr (AMODE == 2) {
    float s = 0.f, ss = 0.f;
    const float* p1 = A1row + lq * 128;
    const float* p2 = A2P ? (A2row + lq * 128) : nullptr;
    #pragma unroll
    for (int k = 0; k < 128; k += 4) {
      float4 v = *reinterpret_cast<const float4*>(p1 + k);
      float vx = v.x, vy = v.y, vz = v.z, vw = v.w;
      if constexpr (A2P) {
        float4 u = *reinterpret_cast<const float4*>(p2 + k);
        vx += u.x; vy += u.y; vz += u.z; vw += u.w;
      }
      s  += vx + vy + vz + vw;
      ss += vx * vx + vy * vy + vz * vz + vw * vw;
    }
    s += __shfl_xor(s, 16); ss += __shfl_xor(ss, 16);
    s += __shfl_xor(s, 32); ss += __shfl_xor(ss, 32);
    mu = s * (1.f / 512.f);
    float var = ss * (1.f / 512.f) - mu * mu;
    rstd = rsqrtf(var + 1e-5f);
  }

  f32x4 acc = {};
  const long ngBase = (long)(n0 >> 4) * 64;

  for (int ks = ks0; ks < ks1; ++ks) {
    const int k0 = ks * 32 + lq * 8;
    FragU ahi, alo;
    {
      float4 v0 = *reinterpret_cast<const float4*>(A1row + k0);
      float4 v1 = *reinterpret_cast<const float4*>(A1row + k0 + 4);
      float t0[8] = {v0.x, v0.y, v0.z, v0.w, v1.x, v1.y, v1.z, v1.w};
      if constexpr (A2P) {
        float4 u0 = *reinterpret_cast<const float4*>(A2row + k0);
        float4 u1 = *reinterpret_cast<const float4*>(A2row + k0 + 4);
        t0[0] += u0.x; t0[1] += u0.y; t0[2] += u0.z; t0[3] += u0.w;
        t0[4] += u1.x; t0[5] += u1.y; t0[6] += u1.z; t0[7] += u1.w;
      }
      if constexpr (AMODE == 2) {
        float4 g0 = *reinterpret_cast<const float4*>(lng + k0);
        float4 g1 = *reinterpret_cast<const float4*>(lng + k0 + 4);
        float4 c0 = *reinterpret_cast<const float4*>(lnb + k0);
        float4 c1 = *reinterpret_cast<const float4*>(lnb + k0 + 4);
        float gg[8] = {g0.x, g0.y, g0.z, g0.w, g1.x, g1.y, g1.z, g1.w};
        float cc[8] = {c0.x, c0.y, c0.z, c0.w, c1.x, c1.y, c1.z, c1.w};
        #pragma unroll
        for (int e = 0; e < 8; ++e) {
          float v = (t0[e] - mu) * rstd * gg[e] + cc[e];
          bsplit(v, ahi.h[e], alo.h[e]);
        }
      } else {
        #pragma unroll
        for (int e = 0; e < 8; ++e) {
          float v = t0[e];
          if constexpr (AMODE == 1) v = fmaxf(v, 0.f);
          bsplit(v, ahi.h[e], alo.h[e]);
        }
      }
    }
    const unsigned short* wp = Wt + ((ngBase + (ks * 4 + lq)) * 16 + l15) * 16;
    s16x8 bhi = *reinterpret_cast<const s16x8*>(wp);
    s16x8 blo = *reinterpret_cast<const s16x8*>(wp + 8);
    acc = mfma16(ahi.s, bhi, acc);
    acc = mfma16(ahi.s, blo, acc);
    acc = mfma16(alo.s, bhi, acc);
  }

  const int mbase = wave * 16 + lq * 4;
  const int n = n0 + l15;
  const float bv = addBias ? bias[n] : 0.f;
  #pragma unroll
  for (int r = 0; r < 4; ++r) {
    const int m = mbase + r;
    float v = acc[r] + bv;
    if (r1) {
      float rv = r1[(long)m * DD + n];
      if (r2) rv += r2[(long)m * DD + n];
      v += fmaxf(rv, 0.f);
    }
    outF[(long)m * DD + n] = v;
  }
}

// ---------------------------------------------------------------------------
// Phase-0: build Wt for w in {0,1,2,7,8,9,10} x 2 arms x 24 blocks.
// grid = 336 slots x 32 ng; 256 threads: t -> (k8 = t>>2, lbase = (t&3)*4).
// ---------------------------------------------------------------------------
__constant__ int c_wmap[7] = {0, 1, 2, 7, 8, 9, 10};

__global__ __launch_bounds__(256) void k_wt(
    const float* __restrict__ WL, const float* __restrict__ WR,
    unsigned short* __restrict__ Wt)
{
  const int bx = blockIdx.x;
  const int ng = bx & 31, slot = bx >> 5;
  const int wi7 = slot % 7, nb2 = slot / 7;
  const int arm = nb2 & 1, nb = nb2 >> 1;
  const float* Wsrc = (arm ? WR : WL) + (long)(nb * 11 + c_wmap[wi7]) * DD * DD;

  const int t = threadIdx.x;
  const int k8 = t >> 2, lbase = (t & 3) * 4;

  unsigned short hi[4][8], lo[4][8];
  #pragma unroll
  for (int e = 0; e < 8; ++e) {
    float4 v = *reinterpret_cast<const float4*>(
        Wsrc + (long)(k8 * 8 + e) * DD + ng * 16 + lbase);
    float vv[4] = {v.x, v.y, v.z, v.w};
    #pragma unroll
    for (int c = 0; c < 4; ++c) {
      __bf16 h, l;
      bsplit(vv[c], h, l);
      union { __bf16 b; unsigned short u; } ch, cl; ch.b = h; cl.b = l;
      hi[c][e] = ch.u; lo[c][e] = cl.u;
    }
  }
  unsigned short* dst = Wt + (long)slot * WT_SLOT
                      + ((long)(ng * 64 + k8) * 16 + lbase) * 16;
  #pragma unroll
  for (int c = 0; c < 4; ++c) {
    s16x8 a, b;
    #pragma unroll
    for (int e = 0; e < 8; ++e) { ((short*)&a)[e] = hi[c][e]; ((short*)&b)[e] = lo[c][e]; }
    *reinterpret_cast<s16x8*>(dst + c * 16)     = a;
    *reinterpret_cast<s16x8*>(dst + c * 16 + 8) = b;
  }
}

// ---------------------------------------------------------------------------
// Phase-1: kt/vt (unchanged from round 2)
// ---------------------------------------------------------------------------
#define LDSW 40

__global__ __launch_bounds__(256) void k_p1t(
    const float* __restrict__ ahs,
    const float* __restrict__ WL, const float* __restrict__ WR,
    const float* __restrict__ bL, const float* __restrict__ bR,
    float* __restrict__ kvt)
{
  __shared__ __align__(16) unsigned short Ab[2][64 * LDSW];
  __shared__ __align__(16) unsigned short Wb[4][2][64 * LDSW];

  const int bx = blockIdx.x;
  const int ntile = bx & 7, mtile = (bx >> 3) & 7, nb = bx >> 6;
  const int n0 = ntile * 64;

  const float* Abase = ahs + (long)(mtile * 25 + nb + 1) * 80 * DD;
  const float* Wp[4];
  const float* bp[4];
  #pragma unroll
  for (int o = 0; o < 4; ++o) {
    const int arm = o >> 1, kv = o & 1;
    Wp[o] = (arm ? WR : WL) + (long)(nb * 11 + 3 + kv) * DD * DD;
    bp[o] = (arm ? bR : bL) + (long)(nb * 11 + 3 + kv) * DD;
  }

  const int tid  = threadIdx.x;
  const int srow = tid >> 2;
  const int skq  = (tid & 3) * 8;
  const int wave = tid >> 6, lane = tid & 63, l15 = lane & 15, lq = lane >> 4;

  f32x4 acc[4][4] = {};
  float aR[8];
  float wRg[4][8];

  auto loadStage = [&](int kbase) {
    const float* ap = Abase + (long)srow * DD + kbase + skq;
    float4 v0 = *reinterpret_cast<const float4*>(ap);
    float4 v1 = *reinterpret_cast<const float4*>(ap + 4);
    aR[0] = v0.x; aR[1] = v0.y; aR[2] = v0.z; aR[3] = v0.w;
    aR[4] = v1.x; aR[5] = v1.y; aR[6] = v1.z; aR[7] = v1.w;
    #pragma unroll
    for (int o = 0; o < 4; ++o) {
      #pragma unroll
      for (int e = 0; e < 8; ++e)
        wRg[o][e] = Wp[o][(long)(kbase + skq + e) * DD + n0 + srow];
    }
  };

  loadStage(0);
  for (int s = 0; s < 16; ++s) {
    __syncthreads();
    {
      FragU uh, ul;
      #pragma unroll
      for (int e = 0; e < 8; ++e) bsplit(aR[e], uh.h[e], ul.h[e]);
      *reinterpret_cast<s16x8*>(&Ab[0][srow * LDSW + skq]) = uh.s;
      *reinterpret_cast<s16x8*>(&Ab[1][srow * LDSW + skq]) = ul.s;
      #pragma unroll
      for (int o = 0; o < 4; ++o) {
        FragU wh, wl;
        #pragma unroll
        for (int e = 0; e < 8; ++e) bsplit(wRg[o][e], wh.h[e], wl.h[e]);
        *reinterpret_cast<s16x8*>(&Wb[o][0][srow * LDSW + skq]) = wh.s;
        *reinterpret_cast<s16x8*>(&Wb[o][1][srow * LDSW + skq]) = wl.s;
      }
    }
    __syncthreads();
    if (s < 15) loadStage((s + 1) * 32);
    s16x8 ahi = *reinterpret_cast<const s16x8*>(&Ab[0][(wave * 16 + l15) * LDSW + lq * 8]);
    s16x8 alo = *reinterpret_cast<const s16x8*>(&Ab[1][(wave * 16 + l15) * LDSW + lq * 8]);
    #pragma unroll
    for (int o = 0; o < 4; ++o) {
      #pragma unroll
      for (int j = 0; j < 4; ++j) {
        s16x8 bhi = *reinterpret_cast<const s16x8*>(&Wb[o][0][(j * 16 + l15) * LDSW + lq * 8]);
        s16x8 blo = *reinterpret_cast<const s16x8*>(&Wb[o][1][(j * 16 + l15) * LDSW + lq * 8]);
        acc[o][j] = mfma16(ahi, bhi, acc[o][j]);
        acc[o][j] = mfma16(ahi, blo, acc[o][j]);
        acc[o][j] = mfma16(alo, bhi, acc[o][j]);
      }
    }
  }

  const int mbase = mtile * 64 + wave * 16 + lq * 4;
  #pragma unroll
  for (int o = 0; o < 4; ++o) {
    float* outb = kvt + (long)(nb * 4 + o) * 512 * DD;
    #pragma unroll
    for (int j = 0; j < 4; ++j) {
      const int n = n0 + j * 16 + l15;
      const float bv = bp[o][n];
      #pragma unroll
      for (int r = 0; r < 4; ++r)
        outb[(long)(mbase + r) * DD + n] = acc[o][j][r] + bv;
    }
  }
}

// Phase-1: ka/va (gather core — runs once, wide)
__global__ __launch_bounds__(256) void k_p1a(
    const float* __restrict__ ahs,
    const float* __restrict__ WL, const float* __restrict__ WR,
    const float* __restrict__ bL, const float* __restrict__ bR,
    float* __restrict__ kva)
{
  const int bx = blockIdx.x;
  const int ntile = bx & 7, kv = (bx >> 3) & 1, arm = (bx >> 4) & 1, nb = bx >> 5;
  const float* Abase = ahs + ((long)(nb + 1) * 80 + 64 + arm * 8) * DD;
  const float* W    = (arm ? WR : WL) + (long)(nb * 11 + 5 + kv) * DD * DD;
  const float* bias = (arm ? bR : bL) + (long)(nb * 11 + 5 + kv) * DD;
  float* out = kva + (long)(nb * 4 + arm * 2 + kv) * 64 * DD;
  gemm64_core<0, false>(Abase, 3, (long)25 * 80 * DD, W, bias,
                        nullptr, nullptr, nullptr, out, ntile * 64);
}

// ---------------------------------------------------------------------------
// Sequential kernels — transposed-weight path
// ---------------------------------------------------------------------------
__global__ __launch_bounds__(256) void k_qkvT(
    const float* __restrict__ xp, const unsigned short* __restrict__ Wt,
    const float* __restrict__ bL, const float* __restrict__ bR,
    float* __restrict__ qkv, int nb)
{
  const int bx = blockIdx.x;
  const int arm = bx / 160;
  const int rem = bx - arm * 160;
  const int wi = rem >> 5, ntile = rem & 31;
  const int sel = (wi < 3) ? arm : (1 - arm);
  const float* A1 = xp + (long)sel * BLK;          // xp[0][sel]
  const float* A2 = xp + (long)(2 + sel) * BLK;    // xp[1][sel]
  const long slot = ((long)nb * 2 + arm) * 7 + wi; // wi 0..4 -> w {0,1,2,7,8}
  const unsigned short* W = Wt + slot * WT_SLOT;
  const float* bias = (arm ? bR : bL) + (long)(nb * 11 + c_wmap[wi]) * DD;
  float* out = qkv + (long)(arm * 5 + wi) * BLK;
  gemm16t<1, true>(A1, A2, W, bias, 1, nullptr, nullptr, nullptr, nullptr,
                   out, ntile * 16, 0, 16);
}

__global__ __launch_bounds__(256) void k_projT(
    const float* __restrict__ attno, const unsigned short* __restrict__ Wt,
    const float* __restrict__ bL, const float* __restrict__ bR,
    const float* __restrict__ xp, float* __restrict__ yp, int nb)
{
  const int bx = blockIdx.x;
  const int arm = bx >> 6;
  const int rem = bx & 63;
  const int kh = rem >> 5, ntile = rem & 31;
  const long slot = ((long)nb * 2 + arm) * 7 + 5;
  const unsigned short* W = Wt + slot * WT_SLOT;
  const float* bias = (arm ? bR : bL) + (long)(nb * 11 + 9) * DD;
  const float* A1 = attno + (long)arm * BLK;
  const float* r1 = (kh == 0) ? xp + (long)arm * BLK : nullptr;
  const float* r2 = (kh == 0) ? xp + (long)(2 + arm) * BLK : nullptr;
  float* out = yp + (long)(kh * 2 + arm) * BLK;
  gemm16t<0, false>(A1, nullptr, W, bias, kh == 0, nullptr, nullptr, r1, r2,
                    out, ntile * 16, kh * 8, kh * 8 + 8);
}

__global__ __launch_bounds__(256) void k_ffnT(
    const float* __restrict__ yp, const unsigned short* __restrict__ Wt,
    const float* __restrict__ bL, const float* __restrict__ bR,
    const float* __restrict__ lngL, const float* __restrict__ lnbL,
    const float* __restrict__ lngR, const float* __restrict__ lnbR,
    float* __restrict__ xp, int nb)
{
  const int bx = blockIdx.x;
  const int arm = bx >> 6;
  const int rem = bx & 63;
  const int kh = rem >> 5, ntile = rem & 31;
  const long slot = ((long)nb * 2 + arm) * 7 + 6;
  const unsigned short* W = Wt + slot * WT_SLOT;
  const float* bias = (arm ? bR : bL) + (long)(nb * 11 + 10) * DD;
  const float* g  = (arm ? lngR : lngL) + (long)nb * DD;
  const float* bb = (arm ? lnbR : lnbL) + (long)nb * DD;
  const float* A1 = yp + (long)arm * BLK;
  const float* A2 = yp + (long)(2 + arm) * BLK;
  float* out = xp + (long)(kh * 2 + arm) * BLK;
  gemm16t<2, true>(A1, A2, W, bias, kh == 0, g, bb, nullptr, nullptr,
                   out, ntile * 16, kh * 8, kh * 8 + 8);
}

// ---------------------------------------------------------------------------
// Sequential fallback (gather path, single-buffer x/y) — used if ws too small
// ---------------------------------------------------------------------------
__global__ __launch_bounds__(256) void k_qkv_g(
    const float* __restrict__ x,
    const float* __restrict__ WL, const float* __restrict__ WR,
    const float* __restrict__ bL, const float* __restrict__ bR,
    float* __restrict__ qkv, int nb)
{
  const int bx = blockIdx.x;
  const int arm = bx / 40;
  const int rem = bx - arm * 40;
  const int wi = rem >> 3, ntile = rem & 7;
  const int w = (wi < 3) ? wi : wi + 4;
  const float* A    = x + (long)((wi < 3) ? arm : (1 - arm)) * BLK;
  const float* W    = (arm ? WR : WL) + (long)(nb * 11 + w) * DD * DD;
  const float* bias = (arm ? bR : bL) + (long)(nb * 11 + w) * DD;
  float* out = qkv + (long)(arm * 5 + wi) * BLK;
  gemm64_core<1, false>(A, 6, 0, W, bias, nullptr, nullptr, nullptr,
                        out, ntile * 64);
}

__global__ __launch_bounds__(256) void k_proj_g(
    const float* __restrict__ attno,
    const float* __restrict__ WL, const float* __restrict__ WR,
    const float* __restrict__ bL, const float* __restrict__ bR,
    const float* __restrict__ x, float* __restrict__ y, int nb)
{
  const int bx = blockIdx.x;
  const int arm = bx >> 3, ntile = bx & 7;
  const float* A    = attno + (long)arm * BLK;
  const float* W    = (arm ? WR : WL) + (long)(nb * 11 + 9) * DD * DD;
  const float* bias = (arm ? bR : bL) + (long)(nb * 11 + 9) * DD;
  gemm64_core<0, true>(A, 6, 0, W, bias, nullptr, nullptr,
                       x + (long)arm * BLK, y + (long)arm * BLK, ntile * 64);
}

__global__ __launch_bounds__(256) void k_ffn_g(
    const float* __restrict__ y,
    const float* __restrict__ WL, const float* __restrict__ WR,
    const float* __restrict__ bL, const float* __restrict__ bR,
    const float* __restrict__ lngL, const float* __restrict__ lnbL,
    const float* __restrict__ lngR, const float* __restrict__ lnbR,
    float* __restrict__ x, int nb)
{
  const int bx = blockIdx.x;
  const int arm = bx >> 3, ntile = bx & 7;
  const float* A    = y + (long)arm * BLK;
  const float* W    = (arm ? WR : WL) + (long)(nb * 11 + 10) * DD * DD;
  const float* bias = (arm ? bR : bL) + (long)(nb * 11 + 10) * DD;
  const float* g    = (arm ? lngR : lngL) + (long)nb * DD;
  const float* bb   = (arm ? lnbR : lnbL) + (long)nb * DD;
  gemm64_core<2, false>(A, 6, 0, W, bias, g, bb, nullptr,
                        x + (long)arm * BLK, ntile * 64);
}

// ---------------------------------------------------------------------------
// Attention per (arm, b, h): keys [ks(rope), ka, g*kt, ki(rope)]
// ---------------------------------------------------------------------------
__global__ __launch_bounds__(512) void k_attn(
    const float* __restrict__ qkv, const float* __restrict__ kvt,
    const float* __restrict__ kva, const float* __restrict__ gating,
    const float* __restrict__ ropeC, const float* __restrict__ ropeS,
    float* __restrict__ attnout, int nb)
{
  __shared__ float kb[88 * 65];
  __shared__ float vb[88 * 65];
  __shared__ float qb[8 * 65];
  __shared__ float pb[8 * 89];

  const int bx = blockIdx.x;
  const int h = bx & 7, b = (bx >> 3) & 7, arm = bx >> 6;
  const int tid = threadIdx.x;
  const float g = tanhf(gating[nb]);

  {
    const int p = tid >> 6, d = tid & 63;
    const float* qrow = qkv + ((long)(arm * 5 + 0) * 64 + b * 8 + p) * DD + h * 64;
    float v = qrow[d], vp = qrow[d ^ 1];
    float c = ropeC[p * 64 + d], s = ropeS[p * 64 + d];
    qb[p * 65 + d] = v * c + ((d & 1) ? vp : -vp) * s;
  }
  for (int idx = tid; idx < 88 * 64; idx += 512) {
    const int j = idx >> 6, d = idx & 63;
    float kvval, vvval;
    if (j < 8) {
      const float* krow = qkv + ((long)(arm * 5 + 1) * 64 + b * 8 + j) * DD + h * 64;
      float v = krow[d], vp = krow[d ^ 1];
      float c = ropeC[j * 64 + d], s = ropeS[j * 64 + d];
      kvval = v * c + ((d & 1) ? vp : -vp) * s;
      vvval = qkv[((long)(arm * 5 + 2) * 64 + b * 8 + j) * DD + h * 64 + d];
    } else if (j < 16) {
      const int t = j - 8;
      kvval = kva[((long)(nb * 4 + arm * 2 + 0) * 64 + b * 8 + t) * DD + h * 64 + d];
      vvval = kva[((long)(nb * 4 + arm * 2 + 1) * 64 + b * 8 + t) * DD + h * 64 + d];
    } else if (j < 80) {
      const int t = j - 16;
      kvval = g * kvt[((long)(nb * 4 + arm * 2 + 0) * 512 + b * 64 + t) * DD + h * 64 + d];
      vvval = kvt[((long)(nb * 4 + arm * 2 + 1) * 512 + b * 64 + t) * DD + h * 64 + d];
    } else {
      const int t = j - 80;
      const float* krow = qkv + ((long)(arm * 5 + 3) * 64 + b * 8 + t) * DD + h * 64;
      float v = krow[d], vp = krow[d ^ 1];
      float c = ropeC[t * 64 + d], s = ropeS[t * 64 + d];
      kvval = v * c + ((d & 1) ? vp : -vp) * s;
      vvval = qkv[((long)(arm * 5 + 4) * 64 + b * 8 + t) * DD + h * 64 + d];
    }
    kb[j * 65 + d] = kvval;
    vb[j * 65 + d] = vvval;
  }
  __syncthreads();

  const int p = tid >> 6, lane = tid & 63;
  float s0 = 0.f, s1 = 0.f;
  const int j2 = 64 + ((lane < 24) ? lane : 0);
  #pragma unroll 8
  for (int d = 0; d < 64; ++d) {
    const float q = qb[p * 65 + d];
    s0 += q * kb[lane * 65 + d];
    s1 += q * kb[j2 * 65 + d];
  }
  s0 *= 0.125f; s1 *= 0.125f;
  float m = (lane < 24) ? fmaxf(s0, s1) : s0;
  #pragma unroll
  for (int off = 1; off < 64; off <<= 1) m = fmaxf(m, __shfl_xor(m, off));
  const float e0 = __expf(s0 - m);
  const float e1 = (lane < 24) ? __expf(s1 - m) : 0.f;
  float sum = e0 + e1;
  #pragma unroll
  for (int off = 1; off < 64; off <<= 1) sum += __shfl_xor(sum, off);
  const float inv = 1.f / sum;
  pb[p * 89 + lane] = e0 * inv;
  if (lane < 24) pb[p * 89 + 64 + lane] = e1 * inv;
  __syncthreads();

  float acc = 0.f;
  #pragma unroll 8
  for (int j = 0; j < 88; ++j) acc += pb[p * 89 + j] * vb[j * 65 + lane];
  attnout[((long)arm * 64 + b * 8 + p) * DD + h * 64 + lane] = acc;
}

// Final: out = LN(relu(xp0+xp1)) @ fcW + fcb
__global__ __launch_bounds__(64) void k_final(
    const float* __restrict__ xp,
    const float* __restrict__ fgL, const float* __restrict__ fbL,
    const float* __restrict__ fgR, const float* __restrict__ fbR,
    const float* __restrict__ fwL, const float* __restrict__ fcbL,
    const float* __restrict__ fwR, const float* __restrict__ fcbR,
    float* __restrict__ out)
{
  const int bx = blockIdx.x;
  const int b = bx & 7, arm = bx >> 3;
  const int tid = threadIdx.x;
  const int p = tid >> 3, k8 = tid & 7;
  const float* xr1 = xp + ((long)arm * 64 + b * 8 + p) * DD;
  const float* xr2 = xr1 + 2 * BLK;

  float s = 0.f, ss = 0.f;
  for (int k = k8 * 64; k < k8 * 64 + 64; k += 4) {
    float4 v = *reinterpret_cast<const float4*>(xr1 + k);
    float4 u = *reinterpret_cast<const float4*>(xr2 + k);
    float a0 = fmaxf(v.x + u.x, 0.f), a1 = fmaxf(v.y + u.y, 0.f);
    float a2 = fmaxf(v.z + u.z, 0.f), a3 = fmaxf(v.w + u.w, 0.f);
    s  += a0 + a1 + a2 + a3;
    ss += a0 * a0 + a1 * a1 + a2 * a2 + a3 * a3;
  }
  s += __shfl_xor(s, 1); ss += __shfl_xor(ss, 1);
  s += __shfl_xor(s, 2); ss += __shfl_xor(ss, 2);
  s += __shfl_xor(s, 4); ss += __shfl_xor(ss, 4);
  const float mu = s * (1.f / 512.f);
  const float var = ss * (1.f / 512.f) - mu * mu;
  const float rstd = rsqrtf(var + 1e-5f);

  const float* g   = arm ? fgR : fgL;
  const float* bb  = arm ? fbR : fbL;
  const float* fw  = arm ? fwR : fwL;
  const float* fcb = arm ? fcbR : fcbL;
  const int j = k8;
  if (j < 7) {
    float acc = 0.f;
    for (int k = 0; k < 512; ++k) {
      const float xv = fmaxf(xr1[k] + xr2[k], 0.f);
      const float xn = (xv - mu) * rstd * g[k] + bb[k];
      acc += xn * fw[k * 7 + j];
    }
    out[((long)(b * 8) + p) * 14 + arm * 7 + j] = acc + fcb[j];
  }
}

// Init: zero xp (both partial sets) + RoPE tables
__global__ void k_init(float* __restrict__ xp, float* __restrict__ ropeC,
                       float* __restrict__ ropeS)
{
  const int t = blockIdx.x * 256 + threadIdx.x;
  if (t < 4 * BLK) xp[t] = 0.f;
  if (t < 512) {
    const int p = t >> 6, d = t & 63;
    const float inv = expf(-(float)(d & 31) * (9.210340371976184f / 32.f));
    const float ang = (float)p * inv;
    ropeC[t] = cosf(ang);
    ropeS[t] = sinf(ang);
  }
}

extern "C" void kernel_launch(void* const* d_in, const int* in_sizes, int n_in,
                              void* d_out, int out_size, void* d_ws, size_t ws_size,
                              hipStream_t stream)
{
  (void)in_sizes; (void)n_in; (void)out_size;

  const float* ahs  = (const float*)d_in[0];
  const float* WL   = (const float*)d_in[1];
  const float* bL   = (const float*)d_in[2];
  const float* lngL = (const float*)d_in[3];
  const float* lnbL = (const float*)d_in[4];
  const float* WR   = (const float*)d_in[5];
  const float* bR   = (const float*)d_in[6];
  const float* lngR = (const float*)d_in[7];
  const float* lnbR = (const float*)d_in[8];
  const float* gating = (const float*)d_in[9];
  const float* fgL  = (const float*)d_in[10];
  const float* fbL  = (const float*)d_in[11];
  const float* fgR  = (const float*)d_in[12];
  const float* fbR  = (const float*)d_in[13];
  const float* fwL  = (const float*)d_in[14];
  const float* fcbL = (const float*)d_in[15];
  const float* fwR  = (const float*)d_in[16];
  const float* fcbR = (const float*)d_in[17];
  float* out = (float*)d_out;

  char* ws = (char*)d_ws;
  size_t off = 0;
  float* ropeC = (float*)(ws + off); off += 512 * 4;
  float* ropeS = (float*)(ws + off); off += 512 * 4;
  float* xp    = (float*)(ws + off); off += (size_t)4 * BLK * 4;   // [kh][arm]
  float* qkv   = (float*)(ws + off); off += (size_t)10 * BLK * 4;
  float* attno = (float*)(ws + off); off += (size_t)2 * BLK * 4;
  float* yp    = (float*)(ws + off); off += (size_t)4 * BLK * 4;   // [kh][arm]
  float* kvt   = (float*)(ws + off); off += (size_t)NBLK * 4 * 512 * DD * 4;
  float* kva   = (float*)(ws + off); off += (size_t)NBLK * 4 * 64 * DD * 4;
  unsigned short* Wt = (unsigned short*)(ws + off);
  const size_t need = off + (size_t)NBLK * 2 * 7 * WT_SLOT * 2;

  const bool useT = (ws_size >= need);

  k_init<<<dim3(512), dim3(256), 0, stream>>>(xp, ropeC, ropeS);
  if (useT)
    k_wt<<<dim3(336 * 32), dim3(256), 0, stream>>>(WL, WR, Wt);
  k_p1t <<<dim3(1536), dim3(256), 0, stream>>>(ahs, WL, WR, bL, bR, kvt);
  k_p1a <<<dim3(768),  dim3(256), 0, stream>>>(ahs, WL, WR, bL, bR, kva);

  for (int nb = 0; nb < NBLK; ++nb) {
    if (useT) {
      k_qkvT<<<dim3(320), dim3(256), 0, stream>>>(xp, Wt, bL, bR, qkv, nb);
      k_attn<<<dim3(128), dim3(512), 0, stream>>>(qkv, kvt, kva, gating, ropeC, ropeS, attno, nb);
      k_projT<<<dim3(128), dim3(256), 0, stream>>>(attno, Wt, bL, bR, xp, yp, nb);
      k_ffnT<<<dim3(128), dim3(256), 0, stream>>>(yp, Wt, bL, bR, lngL, lnbL, lngR, lnbR, xp, nb);
    } else {
      k_qkv_g<<<dim3(80),  dim3(256), 0, stream>>>(xp, WL, WR, bL, bR, qkv, nb);
      k_attn<<<dim3(128), dim3(512), 0, stream>>>(qkv, kvt, kva, gating, ropeC, ropeS, attno, nb);
      k_proj_g<<<dim3(16),  dim3(256), 0, stream>>>(attno, WL, WR, bL, bR, xp, yp, nb);
      k_ffn_g<<<dim3(16),  dim3(256), 0, stream>>>(yp, WL, WR, bL, bR, lngL, lnbL, lngR, lnbR, xp, nb);
    }
  }
  k_final<<<dim3(16), dim3(64), 0, stream>>>(xp, fgL, fbL, fgR, fbR, fwL, fcbL, fwR, fcbR, out);
}